// Round 14
// baseline (439.981 us; speedup 1.0000x reference)
//
#include <hip/hip_runtime.h>
#include <hip/hip_bf16.h>

typedef __bf16 bf16;
typedef __bf16 bf16x4 __attribute__((ext_vector_type(4)));
typedef __bf16 bf16x8 __attribute__((ext_vector_type(8)));
typedef float f32x4 __attribute__((ext_vector_type(4)));

#define MFMA16(a, b, c) __builtin_amdgcn_mfma_f32_16x16x32_bf16(a, b, c, 0, 0, 0)

constexpr int S_LEN = 2048;
constexpr int HDIM = 4096;
constexpr int NHEADS = 32;
constexpr int HEADD = 128;
constexpr int SINKN = 4;
constexpr int RECENT = 204;            // int(2048 * 0.1)
constexpr int EVROWS = SINKN + RECENT; // 208
constexpr float QSCALE = 0.08838834764831845f; // 1/sqrt(128)

// attn jobs: q-block = 128 rows, kv-chunk = 8 tiles of 64 (512 kv)
constexpr int JOBS_PER_HEAD = 40;
constexpr int SLOTS_PER_HEAD = 36;
constexpr size_t SLOT_BYTES = 33792; // 128*128 bf16 + m[128] f32 + l[128] f32

__device__ inline bf16x8 cvt8(const float* p) {
    float4 a = *(const float4*)p;
    float4 b = *(const float4*)(p + 4);
    return bf16x8{(bf16)a.x, (bf16)a.y, (bf16)a.z, (bf16)a.w,
                  (bf16)b.x, (bf16)b.y, (bf16)b.z, (bf16)b.w};
}

__device__ inline void gload16(const bf16* g, bf16* l) {
    __builtin_amdgcn_global_load_lds(
        (const __attribute__((address_space(1))) unsigned int*)g,
        (__attribute__((address_space(3))) unsigned int*)l, 16, 0, 0);
}

// ---------------- f32 -> bf16 conversion (vectorized) ------------------------
__global__ __launch_bounds__(256) void cvt_kernel(const float* __restrict__ in,
                                                  bf16* __restrict__ out, int n8) {
    int i = blockIdx.x * 256 + threadIdx.x;
    if (i >= n8) return;
    *(bf16x8*)(out + (size_t)i * 8) = cvt8(in + (size_t)i * 8);
}

// ================= 8-phase 256x128 GEMM: C[M,N] = A[M,K] @ B[N,K]^T ==========
__device__ __forceinline__ void stage_b256(const bf16* __restrict__ Bp, bf16* dst,
                                           int K, int kc, int tid) {
#pragma unroll
    for (int r = 0; r < 2; ++r) {
        int idx = r * 512 + tid;
        int row = idx >> 3;
        int gs = (idx & 7) ^ (row & 7);
        gload16(Bp + (size_t)row * K + kc + gs * 8, dst + idx * 8);
    }
}
template <int MH>
__device__ __forceinline__ void stage_a256(const bf16* __restrict__ Ap, bf16* dst,
                                           int K, int kc, int tid) {
#pragma unroll
    for (int r = 0; r < 2; ++r) {
        int idx = r * 512 + tid;
        int row = idx >> 3;
        int gs = (idx & 7) ^ (row & 7);
        gload16(Ap + (size_t)(MH * 128 + row) * K + kc + gs * 8,
                dst + MH * 8192 + idx * 8);
    }
}
template <int MH>
__device__ __forceinline__ void lda256(const bf16* buf, int wm, int lg, int lr,
                                       bf16x8 (&af)[2][2]) {
#pragma unroll
    for (int mt = 0; mt < 2; ++mt)
#pragma unroll
        for (int kk = 0; kk < 2; ++kk)
            af[mt][kk] = *(const bf16x8*)&buf[MH * 8192 + (wm * 32 + mt * 16 + lr) * 64 +
                                              (((kk * 4 + lg) ^ (lr & 7)) * 8)];
}
__device__ __forceinline__ void ldb256(const bf16* buf, int wn, int lg, int lr,
                                       bf16x8 (&bfr)[4][2]) {
#pragma unroll
    for (int nt = 0; nt < 4; ++nt)
#pragma unroll
        for (int kk = 0; kk < 2; ++kk)
            bfr[nt][kk] = *(const bf16x8*)&buf[(wn * 64 + nt * 16 + lr) * 64 +
                                               (((kk * 4 + lg) ^ (lr & 7)) * 8)];
}
template <int MH>
__device__ __forceinline__ void mma256(const bf16x8 (&af)[2][2], const bf16x8 (&bfr)[4][2],
                                       f32x4 (&acc)[2][2][4]) {
#pragma unroll
    for (int mt = 0; mt < 2; ++mt)
#pragma unroll
        for (int nt = 0; nt < 4; ++nt)
#pragma unroll
            for (int kk = 0; kk < 2; ++kk)
                acc[MH][mt][nt] = MFMA16(af[mt][kk], bfr[nt][kk], acc[MH][mt][nt]);
}

template <bool C_IS_F32>
__global__ __launch_bounds__(512, 2) void gemm256(const bf16* __restrict__ A,
                                                  const bf16* __restrict__ B,
                                                  void* __restrict__ Cv,
                                                  int M, int N, int K) {
    __shared__ bf16 Abuf[2][256 * 64];
    __shared__ bf16 Bbuf[2][128 * 64];

    const int tid = threadIdx.x;
    const int lane = tid & 63, wid = tid >> 6;
    const int wm = wid >> 1, wn = wid & 1;
    const int lg = lane >> 4, lr = lane & 15;

    const int bid = blockIdx.x;
    const int bx = (bid & 7) * 4 + (bid >> 6);
    const int by = (bid >> 3) & 7;
    const int m0 = by * 256, n0 = bx * 128;

    const bf16* Ap = A + (size_t)m0 * K;
    const bf16* Bp = B + (size_t)n0 * K;

    f32x4 acc[2][2][4] = {};
    bf16x8 af[2][2], bfr[4][2];

    stage_b256(Bp, Bbuf[0], K, 0, tid);
    stage_a256<0>(Ap, Abuf[0], K, 0, tid);
    stage_a256<1>(Ap, Abuf[0], K, 0, tid);
    asm volatile("s_waitcnt vmcnt(2)" ::: "memory");
    __builtin_amdgcn_s_barrier();

    const bf16 *Ard = Abuf[0], *Brd = Bbuf[0];
    bf16 *Awr = Abuf[1], *Bwr = Bbuf[1];

    const int NT = K / 64;
    for (int t = 0; t < NT - 1; ++t) {
        const int kc = (t + 1) * 64;
        ldb256(Brd, wn, lg, lr, bfr);
        lda256<0>(Ard, wm, lg, lr, af);
        stage_b256(Bp, Bwr, K, kc, tid);
        stage_a256<0>(Ap, Awr, K, kc, tid);
        __builtin_amdgcn_s_barrier();
        asm volatile("s_waitcnt lgkmcnt(0)" ::: "memory");
        __builtin_amdgcn_sched_barrier(0);
        __builtin_amdgcn_s_setprio(1);
        mma256<0>(af, bfr, acc);
        __builtin_amdgcn_s_setprio(0);
        asm volatile("s_waitcnt vmcnt(4)" ::: "memory");
        __builtin_amdgcn_s_barrier();
        lda256<1>(Ard, wm, lg, lr, af);
        stage_a256<1>(Ap, Awr, K, kc, tid);
        __builtin_amdgcn_s_barrier();
        asm volatile("s_waitcnt lgkmcnt(0)" ::: "memory");
        __builtin_amdgcn_sched_barrier(0);
        __builtin_amdgcn_s_setprio(1);
        mma256<1>(af, bfr, acc);
        __builtin_amdgcn_s_setprio(0);
        asm volatile("s_waitcnt vmcnt(2)" ::: "memory");
        __builtin_amdgcn_s_barrier();
        const bf16* tA = Ard; Ard = Awr; Awr = (bf16*)tA;
        const bf16* tB = Brd; Brd = Bwr; Bwr = (bf16*)tB;
    }
    asm volatile("s_waitcnt vmcnt(0)" ::: "memory");
    __builtin_amdgcn_s_barrier();
    ldb256(Brd, wn, lg, lr, bfr);
    lda256<0>(Ard, wm, lg, lr, af);
    mma256<0>(af, bfr, acc);
    lda256<1>(Ard, wm, lg, lr, af);
    mma256<1>(af, bfr, acc);

#pragma unroll
    for (int mh = 0; mh < 2; ++mh)
#pragma unroll
        for (int mt = 0; mt < 2; ++mt)
#pragma unroll
            for (int nt = 0; nt < 4; ++nt)
#pragma unroll
                for (int r = 0; r < 4; ++r) {
                    int row = m0 + mh * 128 + wm * 32 + mt * 16 + lg * 4 + r;
                    int col = n0 + wn * 64 + nt * 16 + lr;
                    if constexpr (C_IS_F32)
                        ((float*)Cv)[(size_t)row * N + col] = acc[mh][mt][nt][r];
                    else
                        ((bf16*)Cv)[(size_t)row * N + col] = (bf16)acc[mh][mt][nt][r];
                }
}

// ---------------- RoPE in place on q,k (q also scaled by 1/sqrt(HD)) ---------
__global__ __launch_bounds__(256) void rope_kernel(bf16* __restrict__ q,
                                                   bf16* __restrict__ k) {
    const int s = blockIdx.x;
    const int t = threadIdx.x;
    const int hh = t >> 3;
    const int i0 = (t & 7) << 3;
    const size_t base = (size_t)s * HDIM + hh * HEADD;

    bf16x8 q1 = *(bf16x8*)(q + base + i0);
    bf16x8 q2 = *(bf16x8*)(q + base + 64 + i0);
    bf16x8 k1 = *(bf16x8*)(k + base + i0);
    bf16x8 k2 = *(bf16x8*)(k + base + 64 + i0);
    bf16x8 q1o, q2o, k1o, k2o;
    const float pos = (float)s;
#pragma unroll
    for (int j = 0; j < 8; ++j) {
        float f = pos * exp2f((float)(i0 + j) * (-0.2076205059304602f));
        float sn, cs;
        sincosf(f, &sn, &cs);
        float x1 = (float)q1[j], x2 = (float)q2[j];
        q1o[j] = (bf16)((x1 * cs - x2 * sn) * QSCALE);
        q2o[j] = (bf16)((x2 * cs + x1 * sn) * QSCALE);
        x1 = (float)k1[j]; x2 = (float)k2[j];
        k1o[j] = (bf16)(x1 * cs - x2 * sn);
        k2o[j] = (bf16)(x2 * cs + x1 * sn);
    }
    *(bf16x8*)(q + base + i0) = q1o;
    *(bf16x8*)(q + base + 64 + i0) = q2o;
    *(bf16x8*)(k + base + i0) = k1o;
    *(bf16x8*)(k + base + 64 + i0) = k2o;
}

// ---------------- transpose V: vt[h][d][s] = v[s][h*128+d] -------------------
__global__ __launch_bounds__(256) void transpose_v(const bf16* __restrict__ v,
                                                   bf16* __restrict__ vt) {
    __shared__ bf16 tile[64][136];
    const int h = blockIdx.x;
    const int s0 = blockIdx.y * 64;
    const int tid = threadIdx.x;
#pragma unroll
    for (int j = 0; j < 4; ++j) {
        int ch = tid + 256 * j;
        int row = ch >> 4, c8 = (ch & 15) << 3;
        *(bf16x8*)&tile[row][c8] =
            *(const bf16x8*)(v + (size_t)(s0 + row) * HDIM + h * HEADD + c8);
    }
    __syncthreads();
#pragma unroll
    for (int j = 0; j < 4; ++j) {
        int ch = tid + 256 * j;
        int d = ch >> 3, s8 = (ch & 7) << 3;
        bf16x8 w;
#pragma unroll
        for (int i = 0; i < 8; ++i) w[i] = tile[s8 + i][d];
        *(bf16x8*)(vt + ((size_t)h * HEADD + d) * S_LEN + s0 + s8) = w;
    }
}

// ---------------- flash attention: block = (head, 128 q-rows, <=8 kv-tiles) --
// K double-buffer / V single-buffer software pipeline, counted vmcnt.
// Causal masking branch is wave-uniform-hoisted (skipped on interior tiles).
__global__ __launch_bounds__(256, 2) void attn_kernel(const bf16* __restrict__ q,
                                                      const bf16* __restrict__ k,
                                                      const bf16* __restrict__ vt,
                                                      bf16* __restrict__ o,
                                                      char* __restrict__ partials) {
    __shared__ bf16 K_lds[2][64 * 128];
    __shared__ bf16 V_lds[128 * 64];
    __shared__ bf16 P_lds[4][32 * 72];

    const int tid = threadIdx.x;
    const int lane = tid & 63, wid = tid >> 6;
    const int lg = lane >> 4, lr = lane & 15;

    const int bj = blockIdx.x;
    const int h = bj / JOBS_PER_HEAD;
    const int within = JOBS_PER_HEAD - 1 - (bj % JOBS_PER_HEAD); // heaviest first
    int qb, chunk, nj;
    if (within < 4)       { qb = within; chunk = 0; nj = 1; }
    else if (within < 12) { int u2 = within - 4;  qb = 4  + (u2 >> 1); chunk = u2 & 1;        nj = 2; }
    else if (within < 24) { int u2 = within - 12; int q3 = u2 / 3; qb = 8 + q3; chunk = u2 - 3 * q3; nj = 3; }
    else                  { int u2 = within - 24; qb = 12 + (u2 >> 2); chunk = u2 & 3;        nj = 4; }
    const int q0 = qb * 128;
    const int ntiles = 2 * qb + 2;
    const int tb = chunk * 8;
    const int te = min(tb + 8, ntiles);

    bf16x8 aq[2][4];
#pragma unroll
    for (int rs = 0; rs < 2; ++rs)
#pragma unroll
        for (int dc = 0; dc < 4; ++dc)
            aq[rs][dc] = *(const bf16x8*)(q + (size_t)(q0 + wid * 32 + rs * 16 + lr) * HDIM +
                                          h * HEADD + dc * 32 + lg * 8);

    f32x4 oacc[2][8] = {};
    float m_[2] = {-1e30f, -1e30f};
    float l_[2] = {0.f, 0.f};
    bf16* pw = &P_lds[wid][0];

    // prologue: issue K(tb) into buf 0 (4 loads/wave, stay in flight)
    {
        const int kv0 = tb << 6;
#pragma unroll
        for (int i = 0; i < 4; ++i) {
            const int c = wid * 4 + i;
            const int krow = 4 * c + (lane >> 4);
            const int kg = (lane & 15) ^ (krow & 7);
            gload16(k + (size_t)(kv0 + krow) * HDIM + h * HEADD + kg * 8,
                    &K_lds[0][c * 512]);
        }
    }

    int cur = 0;
    for (int t = tb; t < te; ++t) {
        const int kv0 = t << 6;
        // ---- issue V(t) stage ----
#pragma unroll
        for (int i = 0; i < 4; ++i) {
            const int c = wid * 4 + i;
            const int vrow = 8 * c + (lane >> 3);
            const int vg = (lane & 7) ^ (vrow & 7);
            gload16(vt + (size_t)(h * HEADD + vrow) * S_LEN + kv0 + vg * 8,
                    &V_lds[c * 512]);
        }
        // ---- issue K(t+1) prefetch; await K(t): counted vmcnt ----
        if (t + 1 < te) {
            const int kvn = (t + 1) << 6;
#pragma unroll
            for (int i = 0; i < 4; ++i) {
                const int c = wid * 4 + i;
                const int krow = 4 * c + (lane >> 4);
                const int kg = (lane & 15) ^ (krow & 7);
                gload16(k + (size_t)(kvn + krow) * HDIM + h * HEADD + kg * 8,
                        &K_lds[cur ^ 1][c * 512]);
            }
            asm volatile("s_waitcnt vmcnt(8)" ::: "memory");
        } else {
            asm volatile("s_waitcnt vmcnt(4)" ::: "memory");
        }
        __builtin_amdgcn_s_barrier();
        __builtin_amdgcn_sched_barrier(0);

        // ---- QK^T swapped from K_lds[cur] ----
        const bf16* Kb = &K_lds[cur][0];
        f32x4 st[2][4] = {};
#pragma unroll
        for (int kt = 0; kt < 4; ++kt) {
            bf16x8 kf[4];
#pragma unroll
            for (int dc = 0; dc < 4; ++dc)
                kf[dc] = *(const bf16x8*)&Kb[(kt * 16 + lr) * 128 +
                                             (((dc * 4 + lg) ^ (lr & 7)) * 8)];
#pragma unroll
            for (int dc = 0; dc < 4; ++dc) {
                st[0][kt] = MFMA16(kf[dc], aq[0][dc], st[0][kt]);
                st[1][kt] = MFMA16(kf[dc], aq[1][dc], st[1][kt]);
            }
        }

        // ---- in-lane online softmax (mask branch wave-uniform-hoisted) ----
#pragma unroll
        for (int rs = 0; rs < 2; ++rs) {
            const int qr0 = q0 + wid * 32 + rs * 16;
            float v[16];
            if ((kv0 + 63) > qr0) { // diagonal tile for this rowset (wave-uniform)
                const int qidx = qr0 + lr;
#pragma unroll
                for (int kt = 0; kt < 4; ++kt)
#pragma unroll
                    for (int r = 0; r < 4; ++r) {
                        float x = st[rs][kt][r];
                        if (kv0 + kt * 16 + lg * 4 + r > qidx) x = -1e30f;
                        v[kt * 4 + r] = x;
                    }
            } else {
#pragma unroll
                for (int kt = 0; kt < 4; ++kt)
#pragma unroll
                    for (int r = 0; r < 4; ++r) v[kt * 4 + r] = st[rs][kt][r];
            }
            float pm = v[0];
#pragma unroll
            for (int i = 1; i < 16; ++i) pm = fmaxf(pm, v[i]);
            pm = fmaxf(pm, __shfl_xor(pm, 16));
            pm = fmaxf(pm, __shfl_xor(pm, 32));

            if (__any(pm > m_[rs] + 8.0f)) {
                float mn = fmaxf(m_[rs], pm);
                float sc = __expf(m_[rs] - mn);
                m_[rs] = mn;
                l_[rs] *= sc;
                float scb[4];
#pragma unroll
                for (int r = 0; r < 4; ++r)
                    scb[r] = __uint_as_float(__builtin_amdgcn_ds_bpermute(
                        (lg * 4 + r) * 4, __float_as_uint(sc)));
#pragma unroll
                for (int dt = 0; dt < 8; ++dt)
#pragma unroll
                    for (int r = 0; r < 4; ++r) oacc[rs][dt][r] *= scb[r];
            }
            const float mn = m_[rs];
            float rsum = 0.f;
#pragma unroll
            for (int kt = 0; kt < 4; ++kt) {
                bf16x4 pk;
#pragma unroll
                for (int r = 0; r < 4; ++r) {
                    float p = __expf(v[kt * 4 + r] - mn);
                    rsum += p;
                    pk[r] = (bf16)p;
                }
                *(bf16x4*)&pw[(rs * 16 + lr) * 72 + kt * 16 + lg * 4] = pk;
            }
            rsum += __shfl_xor(rsum, 16);
            rsum += __shfl_xor(rsum, 32);
            l_[rs] += rsum;
        }

        // ---- await V(t); K(t+1) stays in flight ----
        if (t + 1 < te) asm volatile("s_waitcnt vmcnt(4)" ::: "memory");
        else            asm volatile("s_waitcnt vmcnt(0)" ::: "memory");
        __builtin_amdgcn_s_barrier();
        __builtin_amdgcn_sched_barrier(0);

        // ---- PV: A = P rows from per-wave LDS, B = V^T from shared LDS ----
        bf16x8 pa[2][2];
#pragma unroll
        for (int rs = 0; rs < 2; ++rs)
#pragma unroll
            for (int kt2 = 0; kt2 < 2; ++kt2)
                pa[rs][kt2] = *(const bf16x8*)&pw[(rs * 16 + lr) * 72 + kt2 * 32 + lg * 8];
#pragma unroll
        for (int kt2 = 0; kt2 < 2; ++kt2)
#pragma unroll
            for (int dt = 0; dt < 8; ++dt) {
                bf16x8 bv = *(const bf16x8*)&V_lds[(dt * 16 + lr) * 64 +
                                                   (((kt2 * 4 + lg) ^ (lr & 7)) * 8)];
                oacc[0][dt] = MFMA16(pa[0][kt2], bv, oacc[0][dt]);
                oacc[1][dt] = MFMA16(pa[1][kt2], bv, oacc[1][dt]);
            }

        // bar_C: all V/K[cur]/P reads retired before next iteration overwrites
        __builtin_amdgcn_s_barrier();
        __builtin_amdgcn_sched_barrier(0);
        cur ^= 1;
    }

    if (nj == 1) {
#pragma unroll
        for (int rs = 0; rs < 2; ++rs) {
            float lb[4];
#pragma unroll
            for (int r = 0; r < 4; ++r)
                lb[r] = __uint_as_float(__builtin_amdgcn_ds_bpermute(
                    (lg * 4 + r) * 4, __float_as_uint(l_[rs])));
#pragma unroll
            for (int r = 0; r < 4; ++r) {
                float inv = 1.0f / lb[r];
                const int row = q0 + wid * 32 + rs * 16 + lg * 4 + r;
#pragma unroll
                for (int dt = 0; dt < 8; ++dt)
                    o[(size_t)row * HDIM + h * HEADD + dt * 16 + lr] =
                        (bf16)(oacc[rs][dt][r] * inv);
            }
        }
    } else {
        const int sb = (qb < 8) ? (qb - 4) * 2 : (qb < 12) ? 8 + (qb - 8) * 3
                                                           : 20 + (qb - 12) * 4;
        char* slotp = partials + ((size_t)h * SLOTS_PER_HEAD + sb + chunk) * SLOT_BYTES;
        bf16* Op = (bf16*)slotp;
        float* mp = (float*)(slotp + 32768);
        float* lp = mp + 128;
#pragma unroll
        for (int rs = 0; rs < 2; ++rs) {
            const int rowl = wid * 32 + rs * 16;
#pragma unroll
            for (int r = 0; r < 4; ++r)
#pragma unroll
                for (int dt = 0; dt < 8; ++dt)
                    Op[(rowl + lg * 4 + r) * HEADD + dt * 16 + lr] = (bf16)oacc[rs][dt][r];
            if (lg == 0) { mp[rowl + lr] = m_[rs]; lp[rowl + lr] = l_[rs]; }
        }
    }
}

// ---------------- combine partial (O,m,l) chunks -> final O ------------------
__global__ __launch_bounds__(256) void combine_kernel(const char* __restrict__ partials,
                                                      bf16* __restrict__ o) {
    const int h = blockIdx.x;
    const int qb = 4 + blockIdx.y;
    const int nj = (2 * qb + 9) / 8;
    const int sb = (qb < 8) ? (qb - 4) * 2 : (qb < 12) ? 8 + (qb - 8) * 3
                                                       : 20 + (qb - 12) * 4;
    const char* base = partials + ((size_t)h * SLOTS_PER_HEAD + sb) * SLOT_BYTES;

    const int row = threadIdx.x >> 1;
    const int d0 = (threadIdx.x & 1) * 64;

    float mc[4], lc[4];
    float M = -1e30f;
    for (int c = 0; c < nj; ++c) {
        const char* sp = base + (size_t)c * SLOT_BYTES;
        mc[c] = ((const float*)(sp + 32768))[row];
        lc[c] = ((const float*)(sp + 33280))[row];
        M = fmaxf(M, mc[c]);
    }
    float denom = 0.f;
    float acc[64] = {};
    for (int c = 0; c < nj; ++c) {
        float wgt = __expf(mc[c] - M);
        denom += wgt * lc[c];
        const bf16* Op = (const bf16*)(base + (size_t)c * SLOT_BYTES);
#pragma unroll
        for (int j = 0; j < 8; ++j) {
            bf16x8 a = *(const bf16x8*)&Op[row * HEADD + d0 + j * 8];
#pragma unroll
            for (int e = 0; e < 8; ++e) acc[j * 8 + e] += wgt * (float)a[e];
        }
    }
    float inv = 1.0f / denom;
    bf16* dst = o + (size_t)(qb * 128 + row) * HDIM + h * HEADD + d0;
#pragma unroll
    for (int j = 0; j < 8; ++j) {
        bf16x8 w;
#pragma unroll
        for (int e = 0; e < 8; ++e) w[e] = (bf16)(acc[j * 8 + e] * inv);
        *(bf16x8*)&dst[j * 8] = w;
    }
}

// ---------------- eviction copy: k/v sink + recent -> f32 out ----------------
__global__ __launch_bounds__(256) void evict_kernel(const bf16* __restrict__ k,
                                                    const bf16* __restrict__ v,
                                                    float* __restrict__ out) {
    const int total = NHEADS * EVROWS * HEADD;
    int idx = blockIdx.x * 256 + threadIdx.x;
    if (idx >= 2 * total) return;
    const int which = idx / total;
    const int rem = idx % total;
    const int hh = rem / (EVROWS * HEADD);
    const int i = (rem / HEADD) % EVROWS;
    const int d = rem % HEADD;
    const int s = (i < SINKN) ? i : (S_LEN - RECENT) + (i - SINKN);
    const bf16* src = which ? v : k;
    out[(size_t)S_LEN * HDIM + (size_t)which * total + rem] =
        (float)src[(size_t)s * HDIM + hh * HEADD + d];
}

extern "C" void kernel_launch(void* const* d_in, const int* in_sizes, int n_in,
                              void* d_out, int out_size, void* d_ws, size_t ws_size,
                              hipStream_t stream) {
    const float* hs = (const float*)d_in[0];
    const float* Wq = (const float*)d_in[1];
    const float* Wk = (const float*)d_in[2];
    const float* Wv = (const float*)d_in[3];
    const float* Wo = (const float*)d_in[4];
    float* out = (float*)d_out;

    const size_t MB = 1024 * 1024;
    char* w = (char*)d_ws;
    bf16* hs_bf = (bf16*)(w);            // 16 MB (dead after QKV GEMMs)
    bf16* W_bf  = (bf16*)(w + 16 * MB);  // 32 MB (reused for all 4 weights)
    char* part  = w;                     // 38.9 MB partials (reuses 0-48MB region)
    bf16* q_ws  = (bf16*)(w + 48 * MB);  // 16 MB (also o_ws)
    bf16* k_ws  = (bf16*)(w + 64 * MB);  // 16 MB
    bf16* v_ws  = (bf16*)(w + 80 * MB);  // 16 MB
    bf16* vt_ws = (bf16*)(w + 96 * MB);  // 16 MB
    bf16* o_ws  = q_ws;

    const int nW8 = HDIM * HDIM / 8;
    const int nH8 = S_LEN * HDIM / 8;

    cvt_kernel<<<(nH8 + 255) / 256, 256, 0, stream>>>(hs, hs_bf, nH8);

    cvt_kernel<<<(nW8 + 255) / 256, 256, 0, stream>>>(Wq, W_bf, nW8);
    gemm256<false><<<256, 512, 0, stream>>>(hs_bf, W_bf, q_ws, S_LEN, HDIM, HDIM);
    cvt_kernel<<<(nW8 + 255) / 256, 256, 0, stream>>>(Wk, W_bf, nW8);
    gemm256<false><<<256, 512, 0, stream>>>(hs_bf, W_bf, k_ws, S_LEN, HDIM, HDIM);
    cvt_kernel<<<(nW8 + 255) / 256, 256, 0, stream>>>(Wv, W_bf, nW8);
    gemm256<false><<<256, 512, 0, stream>>>(hs_bf, W_bf, v_ws, S_LEN, HDIM, HDIM);

    rope_kernel<<<S_LEN, 256, 0, stream>>>(q_ws, k_ws);
    transpose_v<<<dim3(NHEADS, S_LEN / 64), 256, 0, stream>>>(v_ws, vt_ws);

    evict_kernel<<<(2 * NHEADS * EVROWS * HEADD + 255) / 256, 256, 0, stream>>>(k_ws, v_ws, out);

    attn_kernel<<<NHEADS * JOBS_PER_HEAD, 256, 0, stream>>>(q_ws, k_ws, vt_ws, o_ws, part);
    combine_kernel<<<dim3(NHEADS, 12), 256, 0, stream>>>(part, o_ws);

    cvt_kernel<<<(nW8 + 255) / 256, 256, 0, stream>>>(Wo, W_bf, nW8);
    gemm256<true><<<256, 512, 0, stream>>>(o_ws, W_bf, out, S_LEN, HDIM, HDIM);
}

// Round 15
// 438.173 us; speedup vs baseline: 1.0041x; 1.0041x over previous
//
#include <hip/hip_runtime.h>
#include <hip/hip_bf16.h>

typedef __bf16 bf16;
typedef __bf16 bf16x4 __attribute__((ext_vector_type(4)));
typedef __bf16 bf16x8 __attribute__((ext_vector_type(8)));
typedef float f32x4 __attribute__((ext_vector_type(4)));

#define MFMA16(a, b, c) __builtin_amdgcn_mfma_f32_16x16x32_bf16(a, b, c, 0, 0, 0)

constexpr int S_LEN = 2048;
constexpr int HDIM = 4096;
constexpr int NHEADS = 32;
constexpr int HEADD = 128;
constexpr int SINKN = 4;
constexpr int RECENT = 204;            // int(2048 * 0.1)
constexpr int EVROWS = SINKN + RECENT; // 208
constexpr float QSCALE = 0.08838834764831845f; // 1/sqrt(128)

// attn jobs: q-block = 128 rows, kv-chunk = 8 tiles of 64 (512 kv)
constexpr int JOBS_PER_HEAD = 40;
constexpr int SLOTS_PER_HEAD = 36;
constexpr size_t SLOT_BYTES = 33792; // 128*128 bf16 + m[128] f32 + l[128] f32

__device__ inline bf16x8 cvt8(const float* p) {
    float4 a = *(const float4*)p;
    float4 b = *(const float4*)(p + 4);
    return bf16x8{(bf16)a.x, (bf16)a.y, (bf16)a.z, (bf16)a.w,
                  (bf16)b.x, (bf16)b.y, (bf16)b.z, (bf16)b.w};
}

__device__ inline void gload16(const bf16* g, bf16* l) {
    __builtin_amdgcn_global_load_lds(
        (const __attribute__((address_space(1))) unsigned int*)g,
        (__attribute__((address_space(3))) unsigned int*)l, 16, 0, 0);
}

// ---------------- f32 -> bf16 conversion (vectorized) ------------------------
__global__ __launch_bounds__(256) void cvt_kernel(const float* __restrict__ in,
                                                  bf16* __restrict__ out, int n8) {
    int i = blockIdx.x * 256 + threadIdx.x;
    if (i >= n8) return;
    *(bf16x8*)(out + (size_t)i * 8) = cvt8(in + (size_t)i * 8);
}

// ================= 8-phase 256x128 GEMM: C[M,N] = A[M,K] @ B[N,K]^T ==========
__device__ __forceinline__ void stage_b256(const bf16* __restrict__ Bp, bf16* dst,
                                           int K, int kc, int tid) {
#pragma unroll
    for (int r = 0; r < 2; ++r) {
        int idx = r * 512 + tid;
        int row = idx >> 3;
        int gs = (idx & 7) ^ (row & 7);
        gload16(Bp + (size_t)row * K + kc + gs * 8, dst + idx * 8);
    }
}
template <int MH>
__device__ __forceinline__ void stage_a256(const bf16* __restrict__ Ap, bf16* dst,
                                           int K, int kc, int tid) {
#pragma unroll
    for (int r = 0; r < 2; ++r) {
        int idx = r * 512 + tid;
        int row = idx >> 3;
        int gs = (idx & 7) ^ (row & 7);
        gload16(Ap + (size_t)(MH * 128 + row) * K + kc + gs * 8,
                dst + MH * 8192 + idx * 8);
    }
}
template <int MH>
__device__ __forceinline__ void lda256(const bf16* buf, int wm, int lg, int lr,
                                       bf16x8 (&af)[2][2]) {
#pragma unroll
    for (int mt = 0; mt < 2; ++mt)
#pragma unroll
        for (int kk = 0; kk < 2; ++kk)
            af[mt][kk] = *(const bf16x8*)&buf[MH * 8192 + (wm * 32 + mt * 16 + lr) * 64 +
                                              (((kk * 4 + lg) ^ (lr & 7)) * 8)];
}
__device__ __forceinline__ void ldb256(const bf16* buf, int wn, int lg, int lr,
                                       bf16x8 (&bfr)[4][2]) {
#pragma unroll
    for (int nt = 0; nt < 4; ++nt)
#pragma unroll
        for (int kk = 0; kk < 2; ++kk)
            bfr[nt][kk] = *(const bf16x8*)&buf[(wn * 64 + nt * 16 + lr) * 64 +
                                               (((kk * 4 + lg) ^ (lr & 7)) * 8)];
}
template <int MH>
__device__ __forceinline__ void mma256(const bf16x8 (&af)[2][2], const bf16x8 (&bfr)[4][2],
                                       f32x4 (&acc)[2][2][4]) {
#pragma unroll
    for (int mt = 0; mt < 2; ++mt)
#pragma unroll
        for (int nt = 0; nt < 4; ++nt)
#pragma unroll
            for (int kk = 0; kk < 2; ++kk)
                acc[MH][mt][nt] = MFMA16(af[mt][kk], bfr[nt][kk], acc[MH][mt][nt]);
}

template <bool C_IS_F32>
__global__ __launch_bounds__(512, 2) void gemm256(const bf16* __restrict__ A,
                                                  const bf16* __restrict__ B,
                                                  void* __restrict__ Cv,
                                                  int M, int N, int K) {
    __shared__ bf16 Abuf[2][256 * 64];
    __shared__ bf16 Bbuf[2][128 * 64];

    const int tid = threadIdx.x;
    const int lane = tid & 63, wid = tid >> 6;
    const int wm = wid >> 1, wn = wid & 1;
    const int lg = lane >> 4, lr = lane & 15;

    const int bid = blockIdx.x;
    const int bx = (bid & 7) * 4 + (bid >> 6);
    const int by = (bid >> 3) & 7;
    const int m0 = by * 256, n0 = bx * 128;

    const bf16* Ap = A + (size_t)m0 * K;
    const bf16* Bp = B + (size_t)n0 * K;

    f32x4 acc[2][2][4] = {};
    bf16x8 af[2][2], bfr[4][2];

    stage_b256(Bp, Bbuf[0], K, 0, tid);
    stage_a256<0>(Ap, Abuf[0], K, 0, tid);
    stage_a256<1>(Ap, Abuf[0], K, 0, tid);
    asm volatile("s_waitcnt vmcnt(2)" ::: "memory");
    __builtin_amdgcn_s_barrier();

    const bf16 *Ard = Abuf[0], *Brd = Bbuf[0];
    bf16 *Awr = Abuf[1], *Bwr = Bbuf[1];

    const int NT = K / 64;
    for (int t = 0; t < NT - 1; ++t) {
        const int kc = (t + 1) * 64;
        ldb256(Brd, wn, lg, lr, bfr);
        lda256<0>(Ard, wm, lg, lr, af);
        stage_b256(Bp, Bwr, K, kc, tid);
        stage_a256<0>(Ap, Awr, K, kc, tid);
        __builtin_amdgcn_s_barrier();
        asm volatile("s_waitcnt lgkmcnt(0)" ::: "memory");
        __builtin_amdgcn_sched_barrier(0);
        __builtin_amdgcn_s_setprio(1);
        mma256<0>(af, bfr, acc);
        __builtin_amdgcn_s_setprio(0);
        asm volatile("s_waitcnt vmcnt(4)" ::: "memory");
        __builtin_amdgcn_s_barrier();
        lda256<1>(Ard, wm, lg, lr, af);
        stage_a256<1>(Ap, Awr, K, kc, tid);
        __builtin_amdgcn_s_barrier();
        asm volatile("s_waitcnt lgkmcnt(0)" ::: "memory");
        __builtin_amdgcn_sched_barrier(0);
        __builtin_amdgcn_s_setprio(1);
        mma256<1>(af, bfr, acc);
        __builtin_amdgcn_s_setprio(0);
        asm volatile("s_waitcnt vmcnt(2)" ::: "memory");
        __builtin_amdgcn_s_barrier();
        const bf16* tA = Ard; Ard = Awr; Awr = (bf16*)tA;
        const bf16* tB = Brd; Brd = Bwr; Bwr = (bf16*)tB;
    }
    asm volatile("s_waitcnt vmcnt(0)" ::: "memory");
    __builtin_amdgcn_s_barrier();
    ldb256(Brd, wn, lg, lr, bfr);
    lda256<0>(Ard, wm, lg, lr, af);
    mma256<0>(af, bfr, acc);
    lda256<1>(Ard, wm, lg, lr, af);
    mma256<1>(af, bfr, acc);

#pragma unroll
    for (int mh = 0; mh < 2; ++mh)
#pragma unroll
        for (int mt = 0; mt < 2; ++mt)
#pragma unroll
            for (int nt = 0; nt < 4; ++nt)
#pragma unroll
                for (int r = 0; r < 4; ++r) {
                    int row = m0 + mh * 128 + wm * 32 + mt * 16 + lg * 4 + r;
                    int col = n0 + wn * 64 + nt * 16 + lr;
                    if constexpr (C_IS_F32)
                        ((float*)Cv)[(size_t)row * N + col] = acc[mh][mt][nt][r];
                    else
                        ((bf16*)Cv)[(size_t)row * N + col] = (bf16)acc[mh][mt][nt][r];
                }
}

// ---------------- RoPE in place on q,k (q also scaled by 1/sqrt(HD)) ---------
__global__ __launch_bounds__(256) void rope_kernel(bf16* __restrict__ q,
                                                   bf16* __restrict__ k) {
    const int s = blockIdx.x;
    const int t = threadIdx.x;
    const int hh = t >> 3;
    const int i0 = (t & 7) << 3;
    const size_t base = (size_t)s * HDIM + hh * HEADD;

    bf16x8 q1 = *(bf16x8*)(q + base + i0);
    bf16x8 q2 = *(bf16x8*)(q + base + 64 + i0);
    bf16x8 k1 = *(bf16x8*)(k + base + i0);
    bf16x8 k2 = *(bf16x8*)(k + base + 64 + i0);
    bf16x8 q1o, q2o, k1o, k2o;
    const float pos = (float)s;
#pragma unroll
    for (int j = 0; j < 8; ++j) {
        float f = pos * exp2f((float)(i0 + j) * (-0.2076205059304602f));
        float sn, cs;
        sincosf(f, &sn, &cs);
        float x1 = (float)q1[j], x2 = (float)q2[j];
        q1o[j] = (bf16)((x1 * cs - x2 * sn) * QSCALE);
        q2o[j] = (bf16)((x2 * cs + x1 * sn) * QSCALE);
        x1 = (float)k1[j]; x2 = (float)k2[j];
        k1o[j] = (bf16)(x1 * cs - x2 * sn);
        k2o[j] = (bf16)(x2 * cs + x1 * sn);
    }
    *(bf16x8*)(q + base + i0) = q1o;
    *(bf16x8*)(q + base + 64 + i0) = q2o;
    *(bf16x8*)(k + base + i0) = k1o;
    *(bf16x8*)(k + base + 64 + i0) = k2o;
}

// ---------------- transpose V: vt[h][d][s] = v[s][h*128+d] -------------------
__global__ __launch_bounds__(256) void transpose_v(const bf16* __restrict__ v,
                                                   bf16* __restrict__ vt) {
    __shared__ bf16 tile[64][136];
    const int h = blockIdx.x;
    const int s0 = blockIdx.y * 64;
    const int tid = threadIdx.x;
#pragma unroll
    for (int j = 0; j < 4; ++j) {
        int ch = tid + 256 * j;
        int row = ch >> 4, c8 = (ch & 15) << 3;
        *(bf16x8*)&tile[row][c8] =
            *(const bf16x8*)(v + (size_t)(s0 + row) * HDIM + h * HEADD + c8);
    }
    __syncthreads();
#pragma unroll
    for (int j = 0; j < 4; ++j) {
        int ch = tid + 256 * j;
        int d = ch >> 3, s8 = (ch & 7) << 3;
        bf16x8 w;
#pragma unroll
        for (int i = 0; i < 8; ++i) w[i] = tile[s8 + i][d];
        *(bf16x8*)(vt + ((size_t)h * HEADD + d) * S_LEN + s0 + s8) = w;
    }
}

// ---------------- flash attention: block = (head, 128 q-rows, <=8 kv-tiles) --
// K double-buffer / V single-buffer software pipeline, counted vmcnt.
// Causal masking branch is wave-uniform-hoisted (skipped on interior tiles).
__global__ __launch_bounds__(256, 2) void attn_kernel(const bf16* __restrict__ q,
                                                      const bf16* __restrict__ k,
                                                      const bf16* __restrict__ vt,
                                                      bf16* __restrict__ o,
                                                      char* __restrict__ partials) {
    __shared__ bf16 K_lds[2][64 * 128];
    __shared__ bf16 V_lds[128 * 64];
    __shared__ bf16 P_lds[4][32 * 72];

    const int tid = threadIdx.x;
    const int lane = tid & 63, wid = tid >> 6;
    const int lg = lane >> 4, lr = lane & 15;

    const int bj = blockIdx.x;
    const int h = bj / JOBS_PER_HEAD;
    const int within = JOBS_PER_HEAD - 1 - (bj % JOBS_PER_HEAD); // heaviest first
    int qb, chunk, nj;
    if (within < 4)       { qb = within; chunk = 0; nj = 1; }
    else if (within < 12) { int u2 = within - 4;  qb = 4  + (u2 >> 1); chunk = u2 & 1;        nj = 2; }
    else if (within < 24) { int u2 = within - 12; int q3 = u2 / 3; qb = 8 + q3; chunk = u2 - 3 * q3; nj = 3; }
    else                  { int u2 = within - 24; qb = 12 + (u2 >> 2); chunk = u2 & 3;        nj = 4; }
    const int q0 = qb * 128;
    const int ntiles = 2 * qb + 2;
    const int tb = chunk * 8;
    const int te = min(tb + 8, ntiles);

    bf16x8 aq[2][4];
#pragma unroll
    for (int rs = 0; rs < 2; ++rs)
#pragma unroll
        for (int dc = 0; dc < 4; ++dc)
            aq[rs][dc] = *(const bf16x8*)(q + (size_t)(q0 + wid * 32 + rs * 16 + lr) * HDIM +
                                          h * HEADD + dc * 32 + lg * 8);

    f32x4 oacc[2][8] = {};
    float m_[2] = {-1e30f, -1e30f};
    float l_[2] = {0.f, 0.f};
    bf16* pw = &P_lds[wid][0];

    // prologue: issue K(tb) into buf 0 (4 loads/wave, stay in flight)
    {
        const int kv0 = tb << 6;
#pragma unroll
        for (int i = 0; i < 4; ++i) {
            const int c = wid * 4 + i;
            const int krow = 4 * c + (lane >> 4);
            const int kg = (lane & 15) ^ (krow & 7);
            gload16(k + (size_t)(kv0 + krow) * HDIM + h * HEADD + kg * 8,
                    &K_lds[0][c * 512]);
        }
    }

    int cur = 0;
    for (int t = tb; t < te; ++t) {
        const int kv0 = t << 6;
        // ---- issue V(t) stage ----
#pragma unroll
        for (int i = 0; i < 4; ++i) {
            const int c = wid * 4 + i;
            const int vrow = 8 * c + (lane >> 3);
            const int vg = (lane & 7) ^ (vrow & 7);
            gload16(vt + (size_t)(h * HEADD + vrow) * S_LEN + kv0 + vg * 8,
                    &V_lds[c * 512]);
        }
        // ---- issue K(t+1) prefetch; await K(t): counted vmcnt ----
        if (t + 1 < te) {
            const int kvn = (t + 1) << 6;
#pragma unroll
            for (int i = 0; i < 4; ++i) {
                const int c = wid * 4 + i;
                const int krow = 4 * c + (lane >> 4);
                const int kg = (lane & 15) ^ (krow & 7);
                gload16(k + (size_t)(kvn + krow) * HDIM + h * HEADD + kg * 8,
                        &K_lds[cur ^ 1][c * 512]);
            }
            asm volatile("s_waitcnt vmcnt(8)" ::: "memory");
        } else {
            asm volatile("s_waitcnt vmcnt(4)" ::: "memory");
        }
        __builtin_amdgcn_s_barrier();
        __builtin_amdgcn_sched_barrier(0);

        // ---- QK^T swapped from K_lds[cur] ----
        const bf16* Kb = &K_lds[cur][0];
        f32x4 st[2][4] = {};
#pragma unroll
        for (int kt = 0; kt < 4; ++kt) {
            bf16x8 kf[4];
#pragma unroll
            for (int dc = 0; dc < 4; ++dc)
                kf[dc] = *(const bf16x8*)&Kb[(kt * 16 + lr) * 128 +
                                             (((dc * 4 + lg) ^ (lr & 7)) * 8)];
#pragma unroll
            for (int dc = 0; dc < 4; ++dc) {
                st[0][kt] = MFMA16(kf[dc], aq[0][dc], st[0][kt]);
                st[1][kt] = MFMA16(kf[dc], aq[1][dc], st[1][kt]);
            }
        }

        // ---- in-lane online softmax (mask branch wave-uniform-hoisted) ----
#pragma unroll
        for (int rs = 0; rs < 2; ++rs) {
            const int qr0 = q0 + wid * 32 + rs * 16;
            float v[16];
            if ((kv0 + 63) > qr0) { // diagonal tile for this rowset (wave-uniform)
                const int qidx = qr0 + lr;
#pragma unroll
                for (int kt = 0; kt < 4; ++kt)
#pragma unroll
                    for (int r = 0; r < 4; ++r) {
                        float x = st[rs][kt][r];
                        if (kv0 + kt * 16 + lg * 4 + r > qidx) x = -1e30f;
                        v[kt * 4 + r] = x;
                    }
            } else {
#pragma unroll
                for (int kt = 0; kt < 4; ++kt)
#pragma unroll
                    for (int r = 0; r < 4; ++r) v[kt * 4 + r] = st[rs][kt][r];
            }
            float pm = v[0];
#pragma unroll
            for (int i = 1; i < 16; ++i) pm = fmaxf(pm, v[i]);
            pm = fmaxf(pm, __shfl_xor(pm, 16));
            pm = fmaxf(pm, __shfl_xor(pm, 32));

            if (__any(pm > m_[rs] + 8.0f)) {
                float mn = fmaxf(m_[rs], pm);
                float sc = __expf(m_[rs] - mn);
                m_[rs] = mn;
                l_[rs] *= sc;
                float scb[4];
#pragma unroll
                for (int r = 0; r < 4; ++r)
                    scb[r] = __uint_as_float(__builtin_amdgcn_ds_bpermute(
                        (lg * 4 + r) * 4, __float_as_uint(sc)));
#pragma unroll
                for (int dt = 0; dt < 8; ++dt)
#pragma unroll
                    for (int r = 0; r < 4; ++r) oacc[rs][dt][r] *= scb[r];
            }
            const float mn = m_[rs];
            float rsum = 0.f;
#pragma unroll
            for (int kt = 0; kt < 4; ++kt) {
                bf16x4 pk;
#pragma unroll
                for (int r = 0; r < 4; ++r) {
                    float p = __expf(v[kt * 4 + r] - mn);
                    rsum += p;
                    pk[r] = (bf16)p;
                }
                *(bf16x4*)&pw[(rs * 16 + lr) * 72 + kt * 16 + lg * 4] = pk;
            }
            rsum += __shfl_xor(rsum, 16);
            rsum += __shfl_xor(rsum, 32);
            l_[rs] += rsum;
        }

        // ---- await V(t); K(t+1) stays in flight ----
        if (t + 1 < te) asm volatile("s_waitcnt vmcnt(4)" ::: "memory");
        else            asm volatile("s_waitcnt vmcnt(0)" ::: "memory");
        __builtin_amdgcn_s_barrier();
        __builtin_amdgcn_sched_barrier(0);

        // ---- PV: A = P rows from per-wave LDS, B = V^T from shared LDS ----
        bf16x8 pa[2][2];
#pragma unroll
        for (int rs = 0; rs < 2; ++rs)
#pragma unroll
            for (int kt2 = 0; kt2 < 2; ++kt2)
                pa[rs][kt2] = *(const bf16x8*)&pw[(rs * 16 + lr) * 72 + kt2 * 32 + lg * 8];
#pragma unroll
        for (int kt2 = 0; kt2 < 2; ++kt2)
#pragma unroll
            for (int dt = 0; dt < 8; ++dt) {
                bf16x8 bv = *(const bf16x8*)&V_lds[(dt * 16 + lr) * 64 +
                                                   (((kt2 * 4 + lg) ^ (lr & 7)) * 8)];
                oacc[0][dt] = MFMA16(pa[0][kt2], bv, oacc[0][dt]);
                oacc[1][dt] = MFMA16(pa[1][kt2], bv, oacc[1][dt]);
            }

        // bar_C: all V/K[cur]/P reads retired before next iteration overwrites
        __builtin_amdgcn_s_barrier();
        __builtin_amdgcn_sched_barrier(0);
        cur ^= 1;
    }

    if (nj == 1) {
#pragma unroll
        for (int rs = 0; rs < 2; ++rs) {
            float lb[4];
#pragma unroll
            for (int r = 0; r < 4; ++r)
                lb[r] = __uint_as_float(__builtin_amdgcn_ds_bpermute(
                    (lg * 4 + r) * 4, __float_as_uint(l_[rs])));
#pragma unroll
            for (int r = 0; r < 4; ++r) {
                float inv = 1.0f / lb[r];
                const int row = q0 + wid * 32 + rs * 16 + lg * 4 + r;
#pragma unroll
                for (int dt = 0; dt < 8; ++dt)
                    o[(size_t)row * HDIM + h * HEADD + dt * 16 + lr] =
                        (bf16)(oacc[rs][dt][r] * inv);
            }
        }
    } else {
        const int sb = (qb < 8) ? (qb - 4) * 2 : (qb < 12) ? 8 + (qb - 8) * 3
                                                           : 20 + (qb - 12) * 4;
        char* slotp = partials + ((size_t)h * SLOTS_PER_HEAD + sb + chunk) * SLOT_BYTES;
        bf16* Op = (bf16*)slotp;
        float* mp = (float*)(slotp + 32768);
        float* lp = mp + 128;
#pragma unroll
        for (int rs = 0; rs < 2; ++rs) {
            const int rowl = wid * 32 + rs * 16;
#pragma unroll
            for (int r = 0; r < 4; ++r)
#pragma unroll
                for (int dt = 0; dt < 8; ++dt)
                    Op[(rowl + lg * 4 + r) * HEADD + dt * 16 + lr] = (bf16)oacc[rs][dt][r];
            if (lg == 0) { mp[rowl + lr] = m_[rs]; lp[rowl + lr] = l_[rs]; }
        }
    }
}

// ---------------- combine partial (O,m,l) chunks -> final O ------------------
__global__ __launch_bounds__(256) void combine_kernel(const char* __restrict__ partials,
                                                      bf16* __restrict__ o) {
    const int h = blockIdx.x;
    const int qb = 4 + blockIdx.y;
    const int nj = (2 * qb + 9) / 8;
    const int sb = (qb < 8) ? (qb - 4) * 2 : (qb < 12) ? 8 + (qb - 8) * 3
                                                       : 20 + (qb - 12) * 4;
    const char* base = partials + ((size_t)h * SLOTS_PER_HEAD + sb) * SLOT_BYTES;

    const int row = threadIdx.x >> 1;
    const int d0 = (threadIdx.x & 1) * 64;

    float mc[4], lc[4];
    float M = -1e30f;
    for (int c = 0; c < nj; ++c) {
        const char* sp = base + (size_t)c * SLOT_BYTES;
        mc[c] = ((const float*)(sp + 32768))[row];
        lc[c] = ((const float*)(sp + 33280))[row];
        M = fmaxf(M, mc[c]);
    }
    float denom = 0.f;
    float acc[64] = {};
    for (int c = 0; c < nj; ++c) {
        float wgt = __expf(mc[c] - M);
        denom += wgt * lc[c];
        const bf16* Op = (const bf16*)(base + (size_t)c * SLOT_BYTES);
#pragma unroll
        for (int j = 0; j < 8; ++j) {
            bf16x8 a = *(const bf16x8*)&Op[row * HEADD + d0 + j * 8];
#pragma unroll
            for (int e = 0; e < 8; ++e) acc[j * 8 + e] += wgt * (float)a[e];
        }
    }
    float inv = 1.0f / denom;
    bf16* dst = o + (size_t)(qb * 128 + row) * HDIM + h * HEADD + d0;
#pragma unroll
    for (int j = 0; j < 8; ++j) {
        bf16x8 w;
#pragma unroll
        for (int e = 0; e < 8; ++e) w[e] = (bf16)(acc[j * 8 + e] * inv);
        *(bf16x8*)&dst[j * 8] = w;
    }
}

// ---------------- eviction copy: k/v sink + recent -> f32 out ----------------
__global__ __launch_bounds__(256) void evict_kernel(const bf16* __restrict__ k,
                                                    const bf16* __restrict__ v,
                                                    float* __restrict__ out) {
    const int total = NHEADS * EVROWS * HEADD;
    int idx = blockIdx.x * 256 + threadIdx.x;
    if (idx >= 2 * total) return;
    const int which = idx / total;
    const int rem = idx % total;
    const int hh = rem / (EVROWS * HEADD);
    const int i = (rem / HEADD) % EVROWS;
    const int d = rem % HEADD;
    const int s = (i < SINKN) ? i : (S_LEN - RECENT) + (i - SINKN);
    const bf16* src = which ? v : k;
    out[(size_t)S_LEN * HDIM + (size_t)which * total + rem] =
        (float)src[(size_t)s * HDIM + hh * HEADD + d];
}

extern "C" void kernel_launch(void* const* d_in, const int* in_sizes, int n_in,
                              void* d_out, int out_size, void* d_ws, size_t ws_size,
                              hipStream_t stream) {
    const float* hs = (const float*)d_in[0];
    const float* Wq = (const float*)d_in[1];
    const float* Wk = (const float*)d_in[2];
    const float* Wv = (const float*)d_in[3];
    const float* Wo = (const float*)d_in[4];
    float* out = (float*)d_out;

    const size_t MB = 1024 * 1024;
    char* w = (char*)d_ws;
    bf16* hs_bf = (bf16*)(w);            // 16 MB (dead after QKV GEMMs)
    bf16* W_bf  = (bf16*)(w + 16 * MB);  // 32 MB (reused for all 4 weights)
    char* part  = w;                     // 38.9 MB partials (reuses 0-48MB region)
    bf16* q_ws  = (bf16*)(w + 48 * MB);  // 16 MB (also o_ws)
    bf16* k_ws  = (bf16*)(w + 64 * MB);  // 16 MB
    bf16* v_ws  = (bf16*)(w + 80 * MB);  // 16 MB
    bf16* vt_ws = (bf16*)(w + 96 * MB);  // 16 MB
    bf16* o_ws  = q_ws;

    const int nW8 = HDIM * HDIM / 8;
    const int nH8 = S_LEN * HDIM / 8;

    cvt_kernel<<<(nH8 + 255) / 256, 256, 0, stream>>>(hs, hs_bf, nH8);

    cvt_kernel<<<(nW8 + 255) / 256, 256, 0, stream>>>(Wq, W_bf, nW8);
    gemm256<false><<<256, 512, 0, stream>>>(hs_bf, W_bf, q_ws, S_LEN, HDIM, HDIM);
    cvt_kernel<<<(nW8 + 255) / 256, 256, 0, stream>>>(Wk, W_bf, nW8);
    gemm256<false><<<256, 512, 0, stream>>>(hs_bf, W_bf, k_ws, S_LEN, HDIM, HDIM);
    cvt_kernel<<<(nW8 + 255) / 256, 256, 0, stream>>>(Wv, W_bf, nW8);
    gemm256<false><<<256, 512, 0, stream>>>(hs_bf, W_bf, v_ws, S_LEN, HDIM, HDIM);

    rope_kernel<<<S_LEN, 256, 0, stream>>>(q_ws, k_ws);
    transpose_v<<<dim3(NHEADS, S_LEN / 64), 256, 0, stream>>>(v_ws, vt_ws);

    evict_kernel<<<(2 * NHEADS * EVROWS * HEADD + 255) / 256, 256, 0, stream>>>(k_ws, v_ws, out);

    attn_kernel<<<NHEADS * JOBS_PER_HEAD, 256, 0, stream>>>(q_ws, k_ws, vt_ws, o_ws, part);
    combine_kernel<<<dim3(NHEADS, 12), 256, 0, stream>>>(part, o_ws);

    cvt_kernel<<<(nW8 + 255) / 256, 256, 0, stream>>>(Wo, W_bf, nW8);
    gemm256<true><<<256, 512, 0, stream>>>(o_ws, W_bf, out, S_LEN, HDIM, HDIM);
}